// Round 11
// baseline (125.098 us; speedup 1.0000x reference)
//
#include <hip/hip_runtime.h>

typedef short bf16x8 __attribute__((ext_vector_type(8)));
typedef short bf16x4 __attribute__((ext_vector_type(4)));
typedef float f32x4 __attribute__((ext_vector_type(4)));
typedef int i32x4 __attribute__((ext_vector_type(4)));
typedef int i32x2 __attribute__((ext_vector_type(2)));

#define MFMA16x16x32(a, b, c) __builtin_amdgcn_mfma_f32_16x16x32_bf16(a, b, c, 0, 0, 0)
#define TRR(dst, a) asm volatile("ds_read_b64_tr_b16 %0, %1" : "=v"(dst) : "v"(a))

__device__ __forceinline__ unsigned short f2bf(float f) {
  union { float f; unsigned u; } v; v.f = f;
  unsigned u = v.u + 0x7FFFu + ((v.u >> 16) & 1u);
  return (unsigned short)(u >> 16);
}

__device__ __forceinline__ unsigned cvtpk(float lo, float hi) {
  unsigned r;
  asm("v_cvt_pk_bf16_f32 %0, %1, %2" : "=v"(r) : "v"(lo), "v"(hi));
  return r;
}

__device__ __forceinline__ float max3f(float a, float b, float c) {
  float d;
  asm("v_max3_f32 %0, %1, %2, %3" : "=v"(d) : "v"(a), "v"(b), "v"(c));
  return d;
}

__device__ __forceinline__ void gload16(const void* g, void* l) {
  __builtin_amdgcn_global_load_lds((const __attribute__((address_space(1))) void*)g,
                                   (__attribute__((address_space(3))) void*)l, 16, 0, 0);
}

__device__ __forceinline__ unsigned ldsoff(const void* p) {
  return (unsigned)(unsigned long long)(const __attribute__((address_space(3))) void*)p;
}

// ---------------- fp32 -> bf16 elementwise (x) ----------------
__global__ __launch_bounds__(256) void conv_bf16(const float* __restrict__ in,
                                                 unsigned short* __restrict__ out, int n8) {
  int i = blockIdx.x * 256 + threadIdx.x;
  if (i >= n8) return;
  const float4* p = reinterpret_cast<const float4*>(in + (long)i * 8);
  float4 a = p[0], b = p[1];
  i32x4 o;
  o[0] = cvtpk(a.x, a.y); o[1] = cvtpk(a.z, a.w);
  o[2] = cvtpk(b.x, b.y); o[3] = cvtpk(b.z, b.w);
  *reinterpret_cast<i32x4*>(out + (long)i * 8) = o;
}

// ---------------- transpose + convert: W[K][N] f32 -> Wt[N][K] bf16 ----------------
__global__ __launch_bounds__(256) void trans_f32_bf16(const float* __restrict__ W,
                                                      unsigned short* __restrict__ Wt,
                                                      int K, int N) {
  __shared__ float tile[32][33];
  int n0 = blockIdx.x << 5, k0 = blockIdx.y << 5;
  int tx = threadIdx.x, ty = threadIdx.y;  // 32 x 8
#pragma unroll
  for (int i = 0; i < 32; i += 8)
    tile[ty + i][tx] = W[(long)(k0 + ty + i) * N + n0 + tx];
  __syncthreads();
#pragma unroll
  for (int i = 0; i < 32; i += 8)
    Wt[(long)(n0 + ty + i) * K + k0 + tx] = f2bf(tile[tx][ty + i]);
}

// ---------------- GEMM: C[M,N] = A[M,K] @ Bt[N,K]^T + bias, bf16 inputs ----------------
// 128x128 tile, BK=64 (two 32-k compute phases per staged tile), XCD-aware
// bijective block swizzle (nwg % 8 == 0).
template <int BF16OUT>
__global__ __launch_bounds__(256) void gemm_bt(const unsigned short* __restrict__ A,
                                               const unsigned short* __restrict__ Bt,
                                               const float* __restrict__ bias,
                                               void* __restrict__ Cv,
                                               int M, int N, int K) {
  __shared__ __align__(128) unsigned short As[8192];  // [128][64]
  __shared__ __align__(128) unsigned short Bs[8192];  // [128][64]
  int t = threadIdx.x;
  int w = t >> 6, l = t & 63;
  int g = l >> 4, m16 = l & 15;
  int wr = w >> 1, wc = w & 1;
  // XCD swizzle: bijective since gridDim.x*gridDim.y % 8 == 0
  int nwg = gridDim.x * gridDim.y;
  int f = blockIdx.y * gridDim.x + blockIdx.x;
  int q8 = nwg >> 3;
  int s = (f & 7) * q8 + (f >> 3);
  int bx = s % gridDim.x, by = s / gridDim.x;
  long am0 = (long)by << 7;
  long bn0 = (long)bx << 7;
  f32x4 acc[4][4];
#pragma unroll
  for (int i = 0; i < 4; ++i)
#pragma unroll
    for (int j = 0; j < 4; ++j) acc[i][j] = (f32x4){0.f, 0.f, 0.f, 0.f};

  for (int k0 = 0; k0 < K; k0 += 64) {
#pragma unroll
    for (int i = 0; i < 4; ++i) {
      int seg = i * 4 + w;               // 16 segs of 8 rows x 64 cols
      int flat = (seg << 9) + (l << 3);
      int r_ = flat >> 6, c_ = flat & 63;
      gload16(A + (am0 + r_) * K + k0 + c_, &As[seg << 9]);
      gload16(Bt + (bn0 + r_) * K + k0 + c_, &Bs[seg << 9]);
    }
    asm volatile("s_waitcnt vmcnt(0)" ::: "memory");
    __syncthreads();
#pragma unroll
    for (int kk = 0; kk < 2; ++kk) {
      bf16x8 af[4], bfr[4];
#pragma unroll
      for (int im = 0; im < 4; ++im)
        af[im] = *(const bf16x8*)&As[((wr << 6) + (im << 4) + m16) * 64 + (kk << 5) + (g << 3)];
#pragma unroll
      for (int in = 0; in < 4; ++in)
        bfr[in] = *(const bf16x8*)&Bs[((wc << 6) + (in << 4) + m16) * 64 + (kk << 5) + (g << 3)];
      __builtin_amdgcn_s_setprio(1);
#pragma unroll
      for (int im = 0; im < 4; ++im)
#pragma unroll
        for (int in = 0; in < 4; ++in)
          acc[im][in] = MFMA16x16x32(af[im], bfr[in], acc[im][in]);
      __builtin_amdgcn_s_setprio(0);
    }
    __syncthreads();
  }

#pragma unroll
  for (int im = 0; im < 4; ++im) {
#pragma unroll
    for (int in = 0; in < 4; ++in) {
      long col = bn0 + (wc << 6) + (in << 4) + m16;
      float bval = bias[col];
#pragma unroll
      for (int r = 0; r < 4; ++r) {
        long row = am0 + (wr << 6) + (im << 4) + (g << 2) + r;
        float v = acc[im][in][r] + bval;
        if (BF16OUT)
          ((unsigned short*)Cv)[row * N + col] = f2bf(v);
        else
          ((float*)Cv)[row * N + col] = v;
      }
    }
  }
}

// ---------------- causal flash attention (1 q-tile/block, KVBLK=128, single-buffer) --
// grid: (B*H=32, 32), block 256 (4 waves), 1024 blocks = 4 blocks/CU resident.
// CU-assignment model: block i -> XCD i%8, CU (i/8)%32, so blocks {i, i+256,
// i+512, i+768} co-reside -> co-resident blocks differ by 8 in blockIdx.y.
// qt map: j=yy&7, k=yy>>3 -> qt = {j, 15-j, 16+j, 31-j}[k]. Bijective, and each
// CU's 4 blocks sum to EXACTLY 34 supersteps for every j (was 16 vs 52 with the
// old parity-aliased interleave -> 20% occupancy).
// K tile [128 rows][64 d] LDS (16KB), XOR-swizzled 16B chunks (chunk ^= row&7).
// V tile as 128 subtiles [db 4][kb 32][4key][16d] (128B each, 16KB) for tr_b16.
__global__ __launch_bounds__(256, 3) void attn_fwd(const unsigned short* __restrict__ qkv,
                                                   unsigned short* __restrict__ out) {
  const int D3 = 3072;
  const float C1 = 0.18033688f;    // 0.125 * log2(e)
  const float THR = 11.5415603f;   // 8 * log2(e)
  __shared__ __align__(128) unsigned short Ks[8192];
  __shared__ __align__(128) unsigned short Vs[8192];
  int b = blockIdx.x >> 4, h = blockIdx.x & 15;
  int yy = blockIdx.y;
  int j = yy & 7, k = yy >> 3;
  int qt = (k == 0) ? j : (k == 1) ? (15 - j) : (k == 2) ? (16 + j) : (31 - j);
  int t = threadIdx.x;
  int w = t >> 6, l = t & 63;
  int g = l >> 4, m16 = l & 15;
  long base = (long)b * 2048 * D3;
  const unsigned short* kbase = qkv + base + 1024 + h * 64;
  const unsigned short* vbase = qkv + base + 2048 + h * 64;

  int l8 = l >> 3, sc = l & 7;
  int kof = (w * 8 + l8) * D3 + ((sc ^ l8) << 3);
  int vof = ((w * 8 + l8) * 4 + (sc >> 1)) * D3 + ((sc & 1) << 3);
  const f32x4 zero4 = (f32x4){0.f, 0.f, 0.f, 0.f};

  int qrow = (qt << 6) + (w << 4) + m16;
  const unsigned short* qp = qkv + base + (long)qrow * D3 + h * 64;
  bf16x8 qf0 = *(const bf16x8*)(qp + g * 8);
  bf16x8 qf1 = *(const bf16x8*)(qp + 32 + g * 8);

  f32x4 O[4];
#pragma unroll
  for (int d = 0; d < 4; ++d) O[d] = zero4;
  f32x4 lsv = zero4;
  float m2 = -1e30f;
  int nt = (qt >> 1) + 1;  // supersteps of 128 keys

  for (int ss = 0; ss < nt; ++ss) {
    long off = (long)ss * 128 * D3;
#pragma unroll
    for (int i = 0; i < 4; ++i) {
      gload16(kbase + off + kof + i * 32 * D3, &Ks[(i << 11) + (w << 9)]);
      gload16(vbase + off + vof + (i << 4), &Vs[(i << 11) + (w << 9)]);
    }
    asm volatile("s_waitcnt vmcnt(0)" ::: "memory");  // explicit drain before barrier
    __syncthreads();  // tile ready

    // V transpose-reads issued early; latency hides under QK^T + softmax.
    unsigned va = ldsoff(&Vs[0]) + (g << 7) + (m16 << 3);
    bf16x4 tLo[4][4], tHi[4][4];  // [G 32-key group][d block]
#pragma unroll
    for (int G = 0; G < 4; ++G)
#pragma unroll
      for (int d = 0; d < 4; ++d) {
        unsigned a = va + (G << 10) + (d << 12);
        TRR(tLo[G][d], a);        // kb = 8G+g   -> keys 32G+4g..+3
        TRR(tHi[G][d], a + 512);  // kb = 8G+g+4 -> keys 32G+16+4g..+3
      }
    // K fragments (swizzled) + QK^T
    const char* kbuf = (const char*)&Ks[0];
    int swz = m16 & 7;
    f32x4 st[8];
    __builtin_amdgcn_s_setprio(1);
#pragma unroll
    for (int T = 0; T < 8; ++T) {
      const char* rp = kbuf + (((T << 4) + m16) << 7);
      bf16x8 kf0 = *(const bf16x8*)(rp + ((g ^ swz) << 4));
      bf16x8 kf1 = *(const bf16x8*)(rp + (((4 + g) ^ swz) << 4));
      st[T] = MFMA16x16x32(kf0, qf0, zero4);
      st[T] = MFMA16x16x32(kf1, qf1, st[T]);
    }
    __builtin_amdgcn_s_setprio(0);

    // C layout: col = q = m16, row(T,g,r) -> key = ss*128 + T*16 + g*4 + r
    if (ss == nt - 1) {  // diagonal superstep (wave-uniform branch)
      int rq = qrow - (ss << 7);
#pragma unroll
      for (int T = 0; T < 8; ++T)
#pragma unroll
        for (int r = 0; r < 4; ++r)
          if ((T << 4) + (g << 2) + r > rq) st[T][r] = -3e38f;
    }
    float tm[8];
#pragma unroll
    for (int T = 0; T < 8; ++T)
      tm[T] = max3f(fmaxf(st[T][0], st[T][1]), st[T][2], st[T][3]);
    float u0 = max3f(tm[0], tm[1], tm[2]);
    float u1 = max3f(tm[3], tm[4], tm[5]);
    float tmax = max3f(u0, u1, fmaxf(tm[6], tm[7]));
    tmax = fmaxf(tmax, __shfl_xor(tmax, 16));
    tmax = fmaxf(tmax, __shfl_xor(tmax, 32));
    float tsc2 = tmax * C1;
    bool skip = __all(tsc2 <= m2 + THR);  // defer-max (T13)
    float mnew2 = skip ? m2 : fmaxf(m2, tsc2);
    float p[8][4];
    f32x4 ts4 = zero4;
#pragma unroll
    for (int T = 0; T < 8; ++T)
#pragma unroll
      for (int r = 0; r < 4; ++r) {
        float e = __builtin_amdgcn_exp2f(fmaf(st[T][r], C1, -mnew2));
        p[T][r] = e;
        ts4[r] += e;
      }
    if (!skip) {
      float alpha = __builtin_amdgcn_exp2f(m2 - mnew2);
      lsv *= alpha;
#pragma unroll
      for (int d = 0; d < 4; ++d) O[d] *= alpha;
      m2 = mnew2;
    }
    lsv += ts4;

    bf16x8 pb[4];
#pragma unroll
    for (int G = 0; G < 4; ++G) {
      i32x4 wv;
      wv[0] = cvtpk(p[2 * G][0], p[2 * G][1]);
      wv[1] = cvtpk(p[2 * G][2], p[2 * G][3]);
      wv[2] = cvtpk(p[2 * G + 1][0], p[2 * G + 1][1]);
      wv[3] = cvtpk(p[2 * G + 1][2], p[2 * G + 1][3]);
      pb[G] = __builtin_bit_cast(bf16x8, wv);
    }

    asm volatile("s_waitcnt lgkmcnt(0)" ::: "memory");
    __builtin_amdgcn_sched_barrier(0);

    __builtin_amdgcn_s_setprio(1);
#pragma unroll
    for (int d = 0; d < 4; ++d)
#pragma unroll
      for (int G = 0; G < 4; ++G) {
        bf16x8 vf = __builtin_shufflevector(tLo[G][d], tHi[G][d], 0, 1, 2, 3, 4, 5, 6, 7);
        O[d] = MFMA16x16x32(vf, pb[G], O[d]);
      }
    __builtin_amdgcn_s_setprio(0);
    __syncthreads();  // all reads done before next stage overwrites
  }

  float s = (lsv[0] + lsv[1]) + (lsv[2] + lsv[3]);
  s += __shfl_xor(s, 16);
  s += __shfl_xor(s, 32);
  float inv = 1.0f / s;
  unsigned short* op = out + (long)(b * 2048 + qrow) * 1024 + h * 64;
#pragma unroll
  for (int d = 0; d < 4; ++d) {
    i32x2 pk;
    pk[0] = (int)cvtpk(O[d][0] * inv, O[d][1] * inv);
    pk[1] = (int)cvtpk(O[d][2] * inv, O[d][3] * inv);
    *reinterpret_cast<i32x2*>(op + (d << 4) + (g << 2)) = pk;
  }
}

extern "C" void kernel_launch(void* const* d_in, const int* in_sizes, int n_in,
                              void* d_out, int out_size, void* d_ws, size_t ws_size,
                              hipStream_t stream) {
  const float* x     = (const float*)d_in[0];
  const float* W_qkv = (const float*)d_in[1];
  const float* b_qkv = (const float*)d_in[2];
  const float* W_out = (const float*)d_in[3];
  const float* b_out = (const float*)d_in[4];

  char* ws = (char*)d_ws;
  unsigned short* xb    = (unsigned short*)ws;                  // 8 MB (x bf16; reused as attn out)
  unsigned short* wqkvT = (unsigned short*)(ws + (8l << 20));   // 6 MB
  unsigned short* woutT = (unsigned short*)(ws + (14l << 20));  // 2 MB
  unsigned short* qkv   = (unsigned short*)(ws + (16l << 20));  // 24 MB

  conv_bf16<<<2048, 256, 0, stream>>>(x, xb, 524288);
  trans_f32_bf16<<<dim3(96, 32), dim3(32, 8), 0, stream>>>(W_qkv, wqkvT, 1024, 3072);
  trans_f32_bf16<<<dim3(32, 32), dim3(32, 8), 0, stream>>>(W_out, woutT, 1024, 1024);
  gemm_bt<1><<<dim3(24, 32), 256, 0, stream>>>(xb, wqkvT, b_qkv, (void*)qkv, 4096, 3072, 1024);
  attn_fwd<<<dim3(32, 32), 256, 0, stream>>>(qkv, xb);
  gemm_bt<0><<<dim3(8, 32), 256, 0, stream>>>(xb, woutT, b_out, d_out, 4096, 1024, 1024);
}

// Round 12
// 117.975 us; speedup vs baseline: 1.0604x; 1.0604x over previous
//
#include <hip/hip_runtime.h>

typedef short bf16x8 __attribute__((ext_vector_type(8)));
typedef short bf16x4 __attribute__((ext_vector_type(4)));
typedef float f32x4 __attribute__((ext_vector_type(4)));
typedef int i32x4 __attribute__((ext_vector_type(4)));
typedef int i32x2 __attribute__((ext_vector_type(2)));

#define MFMA16x16x32(a, b, c) __builtin_amdgcn_mfma_f32_16x16x32_bf16(a, b, c, 0, 0, 0)
#define TRR(dst, a) asm volatile("ds_read_b64_tr_b16 %0, %1" : "=v"(dst) : "v"(a))

__device__ __forceinline__ unsigned short f2bf(float f) {
  union { float f; unsigned u; } v; v.f = f;
  unsigned u = v.u + 0x7FFFu + ((v.u >> 16) & 1u);
  return (unsigned short)(u >> 16);
}

__device__ __forceinline__ unsigned cvtpk(float lo, float hi) {
  unsigned r;
  asm("v_cvt_pk_bf16_f32 %0, %1, %2" : "=v"(r) : "v"(lo), "v"(hi));
  return r;
}

__device__ __forceinline__ float max3f(float a, float b, float c) {
  float d;
  asm("v_max3_f32 %0, %1, %2, %3" : "=v"(d) : "v"(a), "v"(b), "v"(c));
  return d;
}

__device__ __forceinline__ void gload16(const void* g, void* l) {
  __builtin_amdgcn_global_load_lds((const __attribute__((address_space(1))) void*)g,
                                   (__attribute__((address_space(3))) void*)l, 16, 0, 0);
}

__device__ __forceinline__ unsigned ldsoff(const void* p) {
  return (unsigned)(unsigned long long)(const __attribute__((address_space(3))) void*)p;
}

// ---------------- fp32 -> bf16 elementwise (x) ----------------
__global__ __launch_bounds__(256) void conv_bf16(const float* __restrict__ in,
                                                 unsigned short* __restrict__ out, int n8) {
  int i = blockIdx.x * 256 + threadIdx.x;
  if (i >= n8) return;
  const float4* p = reinterpret_cast<const float4*>(in + (long)i * 8);
  float4 a = p[0], b = p[1];
  i32x4 o;
  o[0] = cvtpk(a.x, a.y); o[1] = cvtpk(a.z, a.w);
  o[2] = cvtpk(b.x, b.y); o[3] = cvtpk(b.z, b.w);
  *reinterpret_cast<i32x4*>(out + (long)i * 8) = o;
}

// ---------------- transpose + convert: W[K][N] f32 -> Wt[N][K] bf16 ----------------
__global__ __launch_bounds__(256) void trans_f32_bf16(const float* __restrict__ W,
                                                      unsigned short* __restrict__ Wt,
                                                      int K, int N) {
  __shared__ float tile[32][33];
  int n0 = blockIdx.x << 5, k0 = blockIdx.y << 5;
  int tx = threadIdx.x, ty = threadIdx.y;  // 32 x 8
#pragma unroll
  for (int i = 0; i < 32; i += 8)
    tile[ty + i][tx] = W[(long)(k0 + ty + i) * N + n0 + tx];
  __syncthreads();
#pragma unroll
  for (int i = 0; i < 32; i += 8)
    Wt[(long)(n0 + ty + i) * K + k0 + tx] = f2bf(tile[tx][ty + i]);
}

// ---------------- GEMM: C[M,N] = A[M,K] @ Bt[N,K]^T + bias, bf16 inputs ----------------
// 128x128 tile, BK=64, XCD-aware bijective block swizzle (nwg % 8 == 0).
template <int BF16OUT>
__global__ __launch_bounds__(256) void gemm_bt(const unsigned short* __restrict__ A,
                                               const unsigned short* __restrict__ Bt,
                                               const float* __restrict__ bias,
                                               void* __restrict__ Cv,
                                               int M, int N, int K) {
  __shared__ __align__(128) unsigned short As[8192];  // [128][64]
  __shared__ __align__(128) unsigned short Bs[8192];  // [128][64]
  int t = threadIdx.x;
  int w = t >> 6, l = t & 63;
  int g = l >> 4, m16 = l & 15;
  int wr = w >> 1, wc = w & 1;
  int nwg = gridDim.x * gridDim.y;
  int f = blockIdx.y * gridDim.x + blockIdx.x;
  int q8 = nwg >> 3;
  int s = (f & 7) * q8 + (f >> 3);
  int bx = s % gridDim.x, by = s / gridDim.x;
  long am0 = (long)by << 7;
  long bn0 = (long)bx << 7;
  f32x4 acc[4][4];
#pragma unroll
  for (int i = 0; i < 4; ++i)
#pragma unroll
    for (int j = 0; j < 4; ++j) acc[i][j] = (f32x4){0.f, 0.f, 0.f, 0.f};

  for (int k0 = 0; k0 < K; k0 += 64) {
#pragma unroll
    for (int i = 0; i < 4; ++i) {
      int seg = i * 4 + w;               // 16 segs of 8 rows x 64 cols
      int flat = (seg << 9) + (l << 3);
      int r_ = flat >> 6, c_ = flat & 63;
      gload16(A + (am0 + r_) * K + k0 + c_, &As[seg << 9]);
      gload16(Bt + (bn0 + r_) * K + k0 + c_, &Bs[seg << 9]);
    }
    asm volatile("s_waitcnt vmcnt(0)" ::: "memory");
    __syncthreads();
#pragma unroll
    for (int kk = 0; kk < 2; ++kk) {
      bf16x8 af[4], bfr[4];
#pragma unroll
      for (int im = 0; im < 4; ++im)
        af[im] = *(const bf16x8*)&As[((wr << 6) + (im << 4) + m16) * 64 + (kk << 5) + (g << 3)];
#pragma unroll
      for (int in = 0; in < 4; ++in)
        bfr[in] = *(const bf16x8*)&Bs[((wc << 6) + (in << 4) + m16) * 64 + (kk << 5) + (g << 3)];
      __builtin_amdgcn_s_setprio(1);
#pragma unroll
      for (int im = 0; im < 4; ++im)
#pragma unroll
        for (int in = 0; in < 4; ++in)
          acc[im][in] = MFMA16x16x32(af[im], bfr[in], acc[im][in]);
      __builtin_amdgcn_s_setprio(0);
    }
    __syncthreads();
  }

#pragma unroll
  for (int im = 0; im < 4; ++im) {
#pragma unroll
    for (int in = 0; in < 4; ++in) {
      long col = bn0 + (wc << 6) + (in << 4) + m16;
      float bval = bias[col];
#pragma unroll
      for (int r = 0; r < 4; ++r) {
        long row = am0 + (wr << 6) + (im << 4) + (g << 2) + r;
        float v = acc[im][in][r] + bval;
        if (BF16OUT)
          ((unsigned short*)Cv)[row * N + col] = f2bf(v);
        else
          ((float*)Cv)[row * N + col] = v;
      }
    }
  }
}

// ---------------- causal flash attention (KVBLK=64, dbuf, rotated barrier) ----------
// grid: (B*H=32, 32), block 256 (4 waves). 32KB LDS -> 4+ blocks/CU resident.
// Rotated T3 loop: per superstep {vmcnt(0); barrier; issue next-tile stage; compute}.
// The prefetch for tile ss+1 is in flight during the ENTIRE compute of tile ss
// (no trailing drain). vmcnt(0) before the barrier makes each wave's staged data
// visible to all waves after it; the same barrier proves all waves finished
// reading the buffer the new stage overwrites.
// K tile [64 rows][64 d] (8KB), XOR-swizzled 16B chunks (chunk ^= row&7).
// V tile as 64 subtiles [db 4][kb 16][4key][16d] (8KB) for ds_read_b64_tr_b16.
__global__ __launch_bounds__(256, 3) void attn_fwd(const unsigned short* __restrict__ qkv,
                                                   unsigned short* __restrict__ out) {
  const int D3 = 3072;
  const float C1 = 0.18033688f;    // 0.125 * log2(e)
  const float THR = 11.5415603f;   // 8 * log2(e)
  __shared__ __align__(128) unsigned short Ks[2][4096];
  __shared__ __align__(128) unsigned short Vs[2][4096];
  int b = blockIdx.x >> 4, h = blockIdx.x & 15;
  int yy = blockIdx.y;
  int qt = (yy & 1) ? (31 - (yy >> 1)) : (yy >> 1);  // heavy/light interleave
  int t = threadIdx.x;
  int w = t >> 6, l = t & 63;
  int g = l >> 4, m16 = l & 15;
  long base = (long)b * 2048 * D3;
  const unsigned short* kbase = qkv + base + 1024 + h * 64;
  const unsigned short* vbase = qkv + base + 2048 + h * 64;

  // staging offsets (loop-invariant): 2 K chunks + 2 V chunks per thread.
  int l8 = l >> 3, sc = l & 7;
  int kof = (w * 8 + l8) * D3 + ((sc ^ l8) << 3);
  int s0 = w * 8 + l8;  // V subtile: db = s>>4, kb = s&15; load 1 is +32 elems (db+2)
  int vof = ((s0 & 15) * 4 + (sc >> 1)) * D3 + ((s0 >> 4) << 4) + ((sc & 1) << 3);
  const f32x4 zero4 = (f32x4){0.f, 0.f, 0.f, 0.f};

  int qrow = (qt << 6) + (w << 4) + m16;
  const unsigned short* qp = qkv + base + (long)qrow * D3 + h * 64;
  bf16x8 qf0 = *(const bf16x8*)(qp + g * 8);
  bf16x8 qf1 = *(const bf16x8*)(qp + 32 + g * 8);

  f32x4 O[4];
#pragma unroll
  for (int d = 0; d < 4; ++d) O[d] = zero4;
  f32x4 lsv = zero4;
  float m2 = -1e30f;
  int nt = qt + 1;  // supersteps of 64 keys

  // prologue: stage tile 0 into buf 0
  gload16(kbase + kof, &Ks[0][w << 9]);
  gload16(kbase + 32 * D3 + kof, &Ks[0][2048 + (w << 9)]);
  gload16(vbase + vof, &Vs[0][w << 9]);
  gload16(vbase + vof + 32, &Vs[0][2048 + (w << 9)]);

  int buf = 0;
  for (int ss = 0; ss < nt; ++ss) {
    asm volatile("s_waitcnt vmcnt(0)" ::: "memory");  // own stage for cur tile landed
    __syncthreads();  // all waves' stages visible; all done reading buf^1
    if (ss + 1 < nt) {
      long off = (long)(ss + 1) * 64 * D3;
      gload16(kbase + off + kof, &Ks[buf ^ 1][w << 9]);
      gload16(kbase + off + 32 * D3 + kof, &Ks[buf ^ 1][2048 + (w << 9)]);
      gload16(vbase + off + vof, &Vs[buf ^ 1][w << 9]);
      gload16(vbase + off + vof + 32, &Vs[buf ^ 1][2048 + (w << 9)]);
    }

    // V transpose-reads issued early; latency hides under QK^T + softmax.
    unsigned va = ldsoff(&Vs[buf][0]) + (g << 7) + (m16 << 3);
    bf16x4 t0[4], t1[4], t2[4], t3[4];
#pragma unroll
    for (int d = 0; d < 4; ++d) {
      unsigned a = va + (d << 11);
      TRR(t0[d], a);          // kb = g    -> keys 4g..4g+3
      TRR(t1[d], a + 512);    // kb = g+4  -> keys 16+4g..
      TRR(t2[d], a + 1024);   // kb = 8+g  -> keys 32+4g..
      TRR(t3[d], a + 1536);   // kb = 12+g -> keys 48+4g..
    }
    // K fragments (swizzled) + QK^T
    const char* kbuf = (const char*)&Ks[buf][0];
    int swz = m16 & 7;
    f32x4 st[4];
    __builtin_amdgcn_s_setprio(1);
#pragma unroll
    for (int T = 0; T < 4; ++T) {
      const char* rp = kbuf + (((T << 4) + m16) << 7);
      bf16x8 kf0 = *(const bf16x8*)(rp + ((g ^ swz) << 4));
      bf16x8 kf1 = *(const bf16x8*)(rp + (((4 + g) ^ swz) << 4));
      st[T] = MFMA16x16x32(kf0, qf0, zero4);
      st[T] = MFMA16x16x32(kf1, qf1, st[T]);
    }
    __builtin_amdgcn_s_setprio(0);

    // C layout: col = q = m16, row(T,g,r) -> key = ss*64 + T*16 + g*4 + r
    if (ss == nt - 1) {  // diagonal superstep (wave-uniform branch)
      int rq = qrow - (ss << 6);
#pragma unroll
      for (int T = 0; T < 4; ++T)
#pragma unroll
        for (int r = 0; r < 4; ++r)
          if ((T << 4) + (g << 2) + r > rq) st[T][r] = -3e38f;
    }
    float tm[4];
#pragma unroll
    for (int T = 0; T < 4; ++T)
      tm[T] = max3f(fmaxf(st[T][0], st[T][1]), st[T][2], st[T][3]);
    float tmax = fmaxf(max3f(tm[0], tm[1], tm[2]), tm[3]);
    tmax = fmaxf(tmax, __shfl_xor(tmax, 16));
    tmax = fmaxf(tmax, __shfl_xor(tmax, 32));
    float tsc2 = tmax * C1;
    bool skip = __all(tsc2 <= m2 + THR);  // defer-max (T13)
    float mnew2 = skip ? m2 : fmaxf(m2, tsc2);
    float p[4][4];
    f32x4 ts4 = zero4;
#pragma unroll
    for (int T = 0; T < 4; ++T)
#pragma unroll
      for (int r = 0; r < 4; ++r) {
        float e = __builtin_amdgcn_exp2f(fmaf(st[T][r], C1, -mnew2));
        p[T][r] = e;
        ts4[r] += e;
      }
    if (!skip) {
      float alpha = __builtin_amdgcn_exp2f(m2 - mnew2);
      lsv *= alpha;
#pragma unroll
      for (int d = 0; d < 4; ++d) O[d] *= alpha;
      m2 = mnew2;
    }
    lsv += ts4;

    i32x4 w0, w1;
    w0[0] = cvtpk(p[0][0], p[0][1]); w0[1] = cvtpk(p[0][2], p[0][3]);
    w0[2] = cvtpk(p[1][0], p[1][1]); w0[3] = cvtpk(p[1][2], p[1][3]);
    w1[0] = cvtpk(p[2][0], p[2][1]); w1[1] = cvtpk(p[2][2], p[2][3]);
    w1[2] = cvtpk(p[3][0], p[3][1]); w1[3] = cvtpk(p[3][2], p[3][3]);
    bf16x8 pb0 = __builtin_bit_cast(bf16x8, w0);
    bf16x8 pb1 = __builtin_bit_cast(bf16x8, w1);

    asm volatile("s_waitcnt lgkmcnt(0)" ::: "memory");
    __builtin_amdgcn_sched_barrier(0);

    bf16x8 vfA[4], vfB[4];
#pragma unroll
    for (int d = 0; d < 4; ++d) {
      vfA[d] = __builtin_shufflevector(t0[d], t1[d], 0, 1, 2, 3, 4, 5, 6, 7);
      vfB[d] = __builtin_shufflevector(t2[d], t3[d], 0, 1, 2, 3, 4, 5, 6, 7);
    }
    __builtin_amdgcn_s_setprio(1);
#pragma unroll
    for (int d = 0; d < 4; ++d) {
      O[d] = MFMA16x16x32(vfA[d], pb0, O[d]);
      O[d] = MFMA16x16x32(vfB[d], pb1, O[d]);
    }
    __builtin_amdgcn_s_setprio(0);
    buf ^= 1;  // no trailing barrier: next iteration's vmcnt+barrier covers it
  }

  float s = (lsv[0] + lsv[1]) + (lsv[2] + lsv[3]);
  s += __shfl_xor(s, 16);
  s += __shfl_xor(s, 32);
  float inv = 1.0f / s;
  unsigned short* op = out + (long)(b * 2048 + qrow) * 1024 + h * 64;
#pragma unroll
  for (int d = 0; d < 4; ++d) {
    i32x2 pk;
    pk[0] = (int)cvtpk(O[d][0] * inv, O[d][1] * inv);
    pk[1] = (int)cvtpk(O[d][2] * inv, O[d][3] * inv);
    *reinterpret_cast<i32x2*>(op + (d << 4) + (g << 2)) = pk;
  }
}

extern "C" void kernel_launch(void* const* d_in, const int* in_sizes, int n_in,
                              void* d_out, int out_size, void* d_ws, size_t ws_size,
                              hipStream_t stream) {
  const float* x     = (const float*)d_in[0];
  const float* W_qkv = (const float*)d_in[1];
  const float* b_qkv = (const float*)d_in[2];
  const float* W_out = (const float*)d_in[3];
  const float* b_out = (const float*)d_in[4];

  char* ws = (char*)d_ws;
  unsigned short* xb    = (unsigned short*)ws;                  // 8 MB (x bf16; reused as attn out)
  unsigned short* wqkvT = (unsigned short*)(ws + (8l << 20));   // 6 MB
  unsigned short* woutT = (unsigned short*)(ws + (14l << 20));  // 2 MB
  unsigned short* qkv   = (unsigned short*)(ws + (16l << 20));  // 24 MB

  conv_bf16<<<2048, 256, 0, stream>>>(x, xb, 524288);
  trans_f32_bf16<<<dim3(96, 32), dim3(32, 8), 0, stream>>>(W_qkv, wqkvT, 1024, 3072);
  trans_f32_bf16<<<dim3(32, 32), dim3(32, 8), 0, stream>>>(W_out, woutT, 1024, 1024);
  gemm_bt<1><<<dim3(24, 32), 256, 0, stream>>>(xb, wqkvT, b_qkv, (void*)qkv, 4096, 3072, 1024);
  attn_fwd<<<dim3(32, 32), 256, 0, stream>>>(qkv, xb);
  gemm_bt<0><<<dim3(8, 32), 256, 0, stream>>>(xb, woutT, b_out, d_out, 4096, 1024, 1024);
}

// Round 13
// 115.974 us; speedup vs baseline: 1.0787x; 1.0172x over previous
//
#include <hip/hip_runtime.h>

typedef short bf16x8 __attribute__((ext_vector_type(8)));
typedef short bf16x4 __attribute__((ext_vector_type(4)));
typedef float f32x4 __attribute__((ext_vector_type(4)));
typedef int i32x4 __attribute__((ext_vector_type(4)));
typedef int i32x2 __attribute__((ext_vector_type(2)));

#define MFMA16x16x32(a, b, c) __builtin_amdgcn_mfma_f32_16x16x32_bf16(a, b, c, 0, 0, 0)
#define TRR(dst, a) asm volatile("ds_read_b64_tr_b16 %0, %1" : "=v"(dst) : "v"(a))

__device__ __forceinline__ unsigned short f2bf(float f) {
  union { float f; unsigned u; } v; v.f = f;
  unsigned u = v.u + 0x7FFFu + ((v.u >> 16) & 1u);
  return (unsigned short)(u >> 16);
}

__device__ __forceinline__ unsigned cvtpk(float lo, float hi) {
  unsigned r;
  asm("v_cvt_pk_bf16_f32 %0, %1, %2" : "=v"(r) : "v"(lo), "v"(hi));
  return r;
}

__device__ __forceinline__ float max3f(float a, float b, float c) {
  float d;
  asm("v_max3_f32 %0, %1, %2, %3" : "=v"(d) : "v"(a), "v"(b), "v"(c));
  return d;
}

__device__ __forceinline__ void gload16(const void* g, void* l) {
  __builtin_amdgcn_global_load_lds((const __attribute__((address_space(1))) void*)g,
                                   (__attribute__((address_space(3))) void*)l, 16, 0, 0);
}

__device__ __forceinline__ unsigned ldsoff(const void* p) {
  return (unsigned)(unsigned long long)(const __attribute__((address_space(3))) void*)p;
}

// ---------------- fp32 -> bf16 elementwise (x) ----------------
__global__ __launch_bounds__(256) void conv_bf16(const float* __restrict__ in,
                                                 unsigned short* __restrict__ out, int n8) {
  int i = blockIdx.x * 256 + threadIdx.x;
  if (i >= n8) return;
  const float4* p = reinterpret_cast<const float4*>(in + (long)i * 8);
  float4 a = p[0], b = p[1];
  i32x4 o;
  o[0] = cvtpk(a.x, a.y); o[1] = cvtpk(a.z, a.w);
  o[2] = cvtpk(b.x, b.y); o[3] = cvtpk(b.z, b.w);
  *reinterpret_cast<i32x4*>(out + (long)i * 8) = o;
}

// ---------------- transpose + convert: W[K][N] f32 -> Wt[N][K] bf16 ----------------
__global__ __launch_bounds__(256) void trans_f32_bf16(const float* __restrict__ W,
                                                      unsigned short* __restrict__ Wt,
                                                      int K, int N) {
  __shared__ float tile[32][33];
  int n0 = blockIdx.x << 5, k0 = blockIdx.y << 5;
  int tx = threadIdx.x, ty = threadIdx.y;  // 32 x 8
#pragma unroll
  for (int i = 0; i < 32; i += 8)
    tile[ty + i][tx] = W[(long)(k0 + ty + i) * N + n0 + tx];
  __syncthreads();
#pragma unroll
  for (int i = 0; i < 32; i += 8)
    Wt[(long)(n0 + ty + i) * K + k0 + tx] = f2bf(tile[tx][ty + i]);
}

// ---------------- GEMM: C[M,N] = A[M,K] @ Bt[N,K]^T + bias, bf16 inputs ----------------
// 128x128 tile, BK=32, rotated double-buffer: per K-step
// {vmcnt(0); barrier; issue stage(k+1 -> buf^1); compute(k from buf)}.
// Prefetch has the whole 16-MFMA compute phase to land (was: issue+drain
// synchronously every iteration). One barrier per K-step. XCD bijective swizzle.
template <int BF16OUT>
__global__ __launch_bounds__(256) void gemm_bt(const unsigned short* __restrict__ A,
                                               const unsigned short* __restrict__ Bt,
                                               const float* __restrict__ bias,
                                               void* __restrict__ Cv,
                                               int M, int N, int K) {
  __shared__ __align__(128) unsigned short As[2][4096];  // [128][32] x2
  __shared__ __align__(128) unsigned short Bs[2][4096];
  int t = threadIdx.x;
  int w = t >> 6, l = t & 63;
  int g = l >> 4, m16 = l & 15;
  int wr = w >> 1, wc = w & 1;
  int nwg = gridDim.x * gridDim.y;
  int f = blockIdx.y * gridDim.x + blockIdx.x;
  int q8 = nwg >> 3;
  int s = (f & 7) * q8 + (f >> 3);
  int bx = s % gridDim.x, by = s / gridDim.x;
  long am0 = (long)by << 7;
  long bn0 = (long)bx << 7;

  // per-thread staging offsets (loop-invariant)
  int seg0 = w, seg1 = 4 + w;
  int fl0 = (seg0 << 9) + (l << 3), fl1 = (seg1 << 9) + (l << 3);
  int r0 = fl0 >> 5, c0 = fl0 & 31;
  int r1 = fl1 >> 5, c1 = fl1 & 31;

  f32x4 acc[4][4];
#pragma unroll
  for (int i = 0; i < 4; ++i)
#pragma unroll
    for (int j = 0; j < 4; ++j) acc[i][j] = (f32x4){0.f, 0.f, 0.f, 0.f};

  // prologue: stage k0=0 into buf 0
  gload16(A + (am0 + r0) * K + c0, &As[0][seg0 << 9]);
  gload16(A + (am0 + r1) * K + c1, &As[0][seg1 << 9]);
  gload16(Bt + (bn0 + r0) * K + c0, &Bs[0][seg0 << 9]);
  gload16(Bt + (bn0 + r1) * K + c1, &Bs[0][seg1 << 9]);

  int buf = 0;
  for (int k0 = 0; k0 < K; k0 += 32) {
    asm volatile("s_waitcnt vmcnt(0)" ::: "memory");  // own stages landed
    __syncthreads();  // all stages visible; all waves done reading buf^1
    if (k0 + 32 < K) {
      int kn = k0 + 32;
      gload16(A + (am0 + r0) * K + kn + c0, &As[buf ^ 1][seg0 << 9]);
      gload16(A + (am0 + r1) * K + kn + c1, &As[buf ^ 1][seg1 << 9]);
      gload16(Bt + (bn0 + r0) * K + kn + c0, &Bs[buf ^ 1][seg0 << 9]);
      gload16(Bt + (bn0 + r1) * K + kn + c1, &Bs[buf ^ 1][seg1 << 9]);
    }
    bf16x8 af[4], bfr[4];
#pragma unroll
    for (int im = 0; im < 4; ++im)
      af[im] = *(const bf16x8*)&As[buf][((wr << 6) + (im << 4) + m16) * 32 + (g << 3)];
#pragma unroll
    for (int in = 0; in < 4; ++in)
      bfr[in] = *(const bf16x8*)&Bs[buf][((wc << 6) + (in << 4) + m16) * 32 + (g << 3)];
    __builtin_amdgcn_s_setprio(1);
#pragma unroll
    for (int im = 0; im < 4; ++im)
#pragma unroll
      for (int in = 0; in < 4; ++in)
        acc[im][in] = MFMA16x16x32(af[im], bfr[in], acc[im][in]);
    __builtin_amdgcn_s_setprio(0);
    buf ^= 1;  // next iteration's vmcnt+barrier covers reuse
  }

#pragma unroll
  for (int im = 0; im < 4; ++im) {
#pragma unroll
    for (int in = 0; in < 4; ++in) {
      long col = bn0 + (wc << 6) + (in << 4) + m16;
      float bval = bias[col];
#pragma unroll
      for (int r = 0; r < 4; ++r) {
        long row = am0 + (wr << 6) + (im << 4) + (g << 2) + r;
        float v = acc[im][in][r] + bval;
        if (BF16OUT)
          ((unsigned short*)Cv)[row * N + col] = f2bf(v);
        else
          ((float*)Cv)[row * N + col] = v;
      }
    }
  }
}

// ---------------- causal flash attention (KVBLK=64, dbuf, rotated barrier) ----------
// grid: (B*H=32, 32), block 256 (4 waves). 32KB LDS. Rotated T3 loop: per superstep
// {vmcnt(0); barrier; issue next-tile stage; compute}. K tile [64][64] XOR-swizzled;
// V tile as 64 [4key][16d] subtiles for ds_read_b64_tr_b16.
__global__ __launch_bounds__(256, 3) void attn_fwd(const unsigned short* __restrict__ qkv,
                                                   unsigned short* __restrict__ out) {
  const int D3 = 3072;
  const float C1 = 0.18033688f;    // 0.125 * log2(e)
  const float THR = 11.5415603f;   // 8 * log2(e)
  __shared__ __align__(128) unsigned short Ks[2][4096];
  __shared__ __align__(128) unsigned short Vs[2][4096];
  int b = blockIdx.x >> 4, h = blockIdx.x & 15;
  int yy = blockIdx.y;
  int qt = (yy & 1) ? (31 - (yy >> 1)) : (yy >> 1);  // heavy/light interleave
  int t = threadIdx.x;
  int w = t >> 6, l = t & 63;
  int g = l >> 4, m16 = l & 15;
  long base = (long)b * 2048 * D3;
  const unsigned short* kbase = qkv + base + 1024 + h * 64;
  const unsigned short* vbase = qkv + base + 2048 + h * 64;

  int l8 = l >> 3, sc = l & 7;
  int kof = (w * 8 + l8) * D3 + ((sc ^ l8) << 3);
  int s0 = w * 8 + l8;  // V subtile: db = s>>4, kb = s&15; load 1 is +32 elems (db+2)
  int vof = ((s0 & 15) * 4 + (sc >> 1)) * D3 + ((s0 >> 4) << 4) + ((sc & 1) << 3);
  const f32x4 zero4 = (f32x4){0.f, 0.f, 0.f, 0.f};

  int qrow = (qt << 6) + (w << 4) + m16;
  const unsigned short* qp = qkv + base + (long)qrow * D3 + h * 64;
  bf16x8 qf0 = *(const bf16x8*)(qp + g * 8);
  bf16x8 qf1 = *(const bf16x8*)(qp + 32 + g * 8);

  f32x4 O[4];
#pragma unroll
  for (int d = 0; d < 4; ++d) O[d] = zero4;
  f32x4 lsv = zero4;
  float m2 = -1e30f;
  int nt = qt + 1;  // supersteps of 64 keys

  // prologue: stage tile 0 into buf 0
  gload16(kbase + kof, &Ks[0][w << 9]);
  gload16(kbase + 32 * D3 + kof, &Ks[0][2048 + (w << 9)]);
  gload16(vbase + vof, &Vs[0][w << 9]);
  gload16(vbase + vof + 32, &Vs[0][2048 + (w << 9)]);

  int buf = 0;
  for (int ss = 0; ss < nt; ++ss) {
    asm volatile("s_waitcnt vmcnt(0)" ::: "memory");  // own stage for cur tile landed
    __syncthreads();  // all waves' stages visible; all done reading buf^1
    if (ss + 1 < nt) {
      long off = (long)(ss + 1) * 64 * D3;
      gload16(kbase + off + kof, &Ks[buf ^ 1][w << 9]);
      gload16(kbase + off + 32 * D3 + kof, &Ks[buf ^ 1][2048 + (w << 9)]);
      gload16(vbase + off + vof, &Vs[buf ^ 1][w << 9]);
      gload16(vbase + off + vof + 32, &Vs[buf ^ 1][2048 + (w << 9)]);
    }

    // V transpose-reads issued early; latency hides under QK^T + softmax.
    unsigned va = ldsoff(&Vs[buf][0]) + (g << 7) + (m16 << 3);
    bf16x4 t0[4], t1[4], t2[4], t3[4];
#pragma unroll
    for (int d = 0; d < 4; ++d) {
      unsigned a = va + (d << 11);
      TRR(t0[d], a);          // kb = g    -> keys 4g..4g+3
      TRR(t1[d], a + 512);    // kb = g+4  -> keys 16+4g..
      TRR(t2[d], a + 1024);   // kb = 8+g  -> keys 32+4g..
      TRR(t3[d], a + 1536);   // kb = 12+g -> keys 48+4g..
    }
    // K fragments (swizzled) + QK^T
    const char* kbuf = (const char*)&Ks[buf][0];
    int swz = m16 & 7;
    f32x4 st[4];
    __builtin_amdgcn_s_setprio(1);
#pragma unroll
    for (int T = 0; T < 4; ++T) {
      const char* rp = kbuf + (((T << 4) + m16) << 7);
      bf16x8 kf0 = *(const bf16x8*)(rp + ((g ^ swz) << 4));
      bf16x8 kf1 = *(const bf16x8*)(rp + (((4 + g) ^ swz) << 4));
      st[T] = MFMA16x16x32(kf0, qf0, zero4);
      st[T] = MFMA16x16x32(kf1, qf1, st[T]);
    }
    __builtin_amdgcn_s_setprio(0);

    // C layout: col = q = m16, row(T,g,r) -> key = ss*64 + T*16 + g*4 + r
    if (ss == nt - 1) {  // diagonal superstep (wave-uniform branch)
      int rq = qrow - (ss << 6);
#pragma unroll
      for (int T = 0; T < 4; ++T)
#pragma unroll
        for (int r = 0; r < 4; ++r)
          if ((T << 4) + (g << 2) + r > rq) st[T][r] = -3e38f;
    }
    float tm[4];
#pragma unroll
    for (int T = 0; T < 4; ++T)
      tm[T] = max3f(fmaxf(st[T][0], st[T][1]), st[T][2], st[T][3]);
    float tmax = fmaxf(max3f(tm[0], tm[1], tm[2]), tm[3]);
    tmax = fmaxf(tmax, __shfl_xor(tmax, 16));
    tmax = fmaxf(tmax, __shfl_xor(tmax, 32));
    float tsc2 = tmax * C1;
    bool skip = __all(tsc2 <= m2 + THR);  // defer-max (T13)
    float mnew2 = skip ? m2 : fmaxf(m2, tsc2);
    float p[4][4];
    f32x4 ts4 = zero4;
#pragma unroll
    for (int T = 0; T < 4; ++T)
#pragma unroll
      for (int r = 0; r < 4; ++r) {
        float e = __builtin_amdgcn_exp2f(fmaf(st[T][r], C1, -mnew2));
        p[T][r] = e;
        ts4[r] += e;
      }
    if (!skip) {
      float alpha = __builtin_amdgcn_exp2f(m2 - mnew2);
      lsv *= alpha;
#pragma unroll
      for (int d = 0; d < 4; ++d) O[d] *= alpha;
      m2 = mnew2;
    }
    lsv += ts4;

    i32x4 w0, w1;
    w0[0] = cvtpk(p[0][0], p[0][1]); w0[1] = cvtpk(p[0][2], p[0][3]);
    w0[2] = cvtpk(p[1][0], p[1][1]); w0[3] = cvtpk(p[1][2], p[1][3]);
    w1[0] = cvtpk(p[2][0], p[2][1]); w1[1] = cvtpk(p[2][2], p[2][3]);
    w1[2] = cvtpk(p[3][0], p[3][1]); w1[3] = cvtpk(p[3][2], p[3][3]);
    bf16x8 pb0 = __builtin_bit_cast(bf16x8, w0);
    bf16x8 pb1 = __builtin_bit_cast(bf16x8, w1);

    asm volatile("s_waitcnt lgkmcnt(0)" ::: "memory");
    __builtin_amdgcn_sched_barrier(0);

    bf16x8 vfA[4], vfB[4];
#pragma unroll
    for (int d = 0; d < 4; ++d) {
      vfA[d] = __builtin_shufflevector(t0[d], t1[d], 0, 1, 2, 3, 4, 5, 6, 7);
      vfB[d] = __builtin_shufflevector(t2[d], t3[d], 0, 1, 2, 3, 4, 5, 6, 7);
    }
    __builtin_amdgcn_s_setprio(1);
#pragma unroll
    for (int d = 0; d < 4; ++d) {
      O[d] = MFMA16x16x32(vfA[d], pb0, O[d]);
      O[d] = MFMA16x16x32(vfB[d], pb1, O[d]);
    }
    __builtin_amdgcn_s_setprio(0);
    buf ^= 1;  // no trailing barrier: next iteration's vmcnt+barrier covers it
  }

  float s = (lsv[0] + lsv[1]) + (lsv[2] + lsv[3]);
  s += __shfl_xor(s, 16);
  s += __shfl_xor(s, 32);
  float inv = 1.0f / s;
  unsigned short* op = out + (long)(b * 2048 + qrow) * 1024 + h * 64;
#pragma unroll
  for (int d = 0; d < 4; ++d) {
    i32x2 pk;
    pk[0] = (int)cvtpk(O[d][0] * inv, O[d][1] * inv);
    pk[1] = (int)cvtpk(O[d][2] * inv, O[d][3] * inv);
    *reinterpret_cast<i32x2*>(op + (d << 4) + (g << 2)) = pk;
  }
}

extern "C" void kernel_launch(void* const* d_in, const int* in_sizes, int n_in,
                              void* d_out, int out_size, void* d_ws, size_t ws_size,
                              hipStream_t stream) {
  const float* x     = (const float*)d_in[0];
  const float* W_qkv = (const float*)d_in[1];
  const float* b_qkv = (const float*)d_in[2];
  const float* W_out = (const float*)d_in[3];
  const float* b_out = (const float*)d_in[4];

  char* ws = (char*)d_ws;
  unsigned short* xb    = (unsigned short*)ws;                  // 8 MB (x bf16; reused as attn out)
  unsigned short* wqkvT = (unsigned short*)(ws + (8l << 20));   // 6 MB
  unsigned short* woutT = (unsigned short*)(ws + (14l << 20));  // 2 MB
  unsigned short* qkv   = (unsigned short*)(ws + (16l << 20));  // 24 MB

  conv_bf16<<<2048, 256, 0, stream>>>(x, xb, 524288);
  trans_f32_bf16<<<dim3(96, 32), dim3(32, 8), 0, stream>>>(W_qkv, wqkvT, 1024, 3072);
  trans_f32_bf16<<<dim3(32, 32), dim3(32, 8), 0, stream>>>(W_out, woutT, 1024, 1024);
  gemm_bt<1><<<dim3(24, 32), 256, 0, stream>>>(xb, wqkvT, b_qkv, (void*)qkv, 4096, 3072, 1024);
  attn_fwd<<<dim3(32, 32), 256, 0, stream>>>(qkv, xb);
  gemm_bt<0><<<dim3(8, 32), 256, 0, stream>>>(xb, woutT, b_out, d_out, 4096, 1024, 1024);
}

// Round 14
// 110.428 us; speedup vs baseline: 1.1328x; 1.0502x over previous
//
#include <hip/hip_runtime.h>

typedef short bf16x8 __attribute__((ext_vector_type(8)));
typedef short bf16x4 __attribute__((ext_vector_type(4)));
typedef float f32x4 __attribute__((ext_vector_type(4)));
typedef int i32x4 __attribute__((ext_vector_type(4)));
typedef int i32x2 __attribute__((ext_vector_type(2)));

#define MFMA16x16x32(a, b, c) __builtin_amdgcn_mfma_f32_16x16x32_bf16(a, b, c, 0, 0, 0)
#define TRR(dst, a) asm volatile("ds_read_b64_tr_b16 %0, %1" : "=v"(dst) : "v"(a))

__device__ __forceinline__ unsigned short f2bf(float f) {
  union { float f; unsigned u; } v; v.f = f;
  unsigned u = v.u + 0x7FFFu + ((v.u >> 16) & 1u);
  return (unsigned short)(u >> 16);
}

__device__ __forceinline__ unsigned cvtpk(float lo, float hi) {
  unsigned r;
  asm("v_cvt_pk_bf16_f32 %0, %1, %2" : "=v"(r) : "v"(lo), "v"(hi));
  return r;
}

__device__ __forceinline__ float max3f(float a, float b, float c) {
  float d;
  asm("v_max3_f32 %0, %1, %2, %3" : "=v"(d) : "v"(a), "v"(b), "v"(c));
  return d;
}

__device__ __forceinline__ void gload16(const void* g, void* l) {
  __builtin_amdgcn_global_load_lds((const __attribute__((address_space(1))) void*)g,
                                   (__attribute__((address_space(3))) void*)l, 16, 0, 0);
}

__device__ __forceinline__ unsigned ldsoff(const void* p) {
  return (unsigned)(unsigned long long)(const __attribute__((address_space(3))) void*)p;
}

// ---------------- fused prep: x->bf16, W_qkv^T->bf16, W_out^T->bf16 ----------------
// grid 6144 x 256: [0,2048) conv x; [2048,5120) transpose W_qkv; [5120,6144) W_out.
__global__ __launch_bounds__(256) void prep(const float* __restrict__ x,
                                            unsigned short* __restrict__ xb,
                                            const float* __restrict__ Wq,
                                            unsigned short* __restrict__ WqT,
                                            const float* __restrict__ Wo,
                                            unsigned short* __restrict__ WoT) {
  __shared__ float tile[32][33];
  int bid = blockIdx.x;
  int t = threadIdx.x;
  if (bid < 2048) {
    long i = (long)bid * 256 + t;
    const float4* p = reinterpret_cast<const float4*>(x + i * 8);
    float4 a = p[0], b = p[1];
    i32x4 o;
    o[0] = cvtpk(a.x, a.y); o[1] = cvtpk(a.z, a.w);
    o[2] = cvtpk(b.x, b.y); o[3] = cvtpk(b.z, b.w);
    *reinterpret_cast<i32x4*>(xb + i * 8) = o;
    return;
  }
  const float* W; unsigned short* Wt; int N, bx, by;
  if (bid < 5120) {
    W = Wq; Wt = WqT; N = 3072;
    int r = bid - 2048; bx = r % 96; by = r / 96;
  } else {
    W = Wo; Wt = WoT; N = 1024;
    int r = bid - 5120; bx = r & 31; by = r >> 5;
  }
  const int K = 1024;
  int tx = t & 31, ty = t >> 5;  // 32 x 8
  int n0 = bx << 5, k0 = by << 5;
#pragma unroll
  for (int i = 0; i < 32; i += 8)
    tile[ty + i][tx] = W[(long)(k0 + ty + i) * N + n0 + tx];
  __syncthreads();
#pragma unroll
  for (int i = 0; i < 32; i += 8)
    Wt[(long)(n0 + ty + i) * K + k0 + tx] = f2bf(tile[tx][ty + i]);
}

// ---------------- GEMM: C[M,N] = A[M,K] @ Bt[N,K]^T + bias, bf16 inputs ----------------
// 128x128 tile, BK=32, 3-buffer depth-2 prefetch with COUNTED vmcnt (T4):
// prologue stages tiles 0,1; per K-step: wait vmcnt(4) (tile k landed, tile k+1
// still in flight) -> barrier -> issue tile k+2 -> compute tile k. The stage for
// tile k had the entire previous iteration (compute+barrier) to land. Buffer
// (k+2)%3 held tile k-1 whose compute finished before this barrier. XCD swizzle.
template <int BF16OUT>
__global__ __launch_bounds__(256) void gemm_bt(const unsigned short* __restrict__ A,
                                               const unsigned short* __restrict__ Bt,
                                               const float* __restrict__ bias,
                                               void* __restrict__ Cv,
                                               int M, int N, int K) {
  __shared__ __align__(128) unsigned short As[3][4096];  // [128][32] x3
  __shared__ __align__(128) unsigned short Bs[3][4096];
  int t = threadIdx.x;
  int w = t >> 6, l = t & 63;
  int g = l >> 4, m16 = l & 15;
  int wr = w >> 1, wc = w & 1;
  int nwg = gridDim.x * gridDim.y;
  int f = blockIdx.y * gridDim.x + blockIdx.x;
  int q8 = nwg >> 3;
  int s = (f & 7) * q8 + (f >> 3);
  int bx = s % gridDim.x, by = s / gridDim.x;
  long am0 = (long)by << 7;
  long bn0 = (long)bx << 7;

  // per-thread staging offsets (loop-invariant)
  int seg0 = w, seg1 = 4 + w;
  int fl0 = (seg0 << 9) + (l << 3), fl1 = (seg1 << 9) + (l << 3);
  int r0 = fl0 >> 5, c0 = fl0 & 31;
  int r1 = fl1 >> 5, c1 = fl1 & 31;

  f32x4 acc[4][4];
#pragma unroll
  for (int i = 0; i < 4; ++i)
#pragma unroll
    for (int j = 0; j < 4; ++j) acc[i][j] = (f32x4){0.f, 0.f, 0.f, 0.f};

  // prologue: stage tiles 0 and 1
  gload16(A + (am0 + r0) * K + c0, &As[0][seg0 << 9]);
  gload16(A + (am0 + r1) * K + c1, &As[0][seg1 << 9]);
  gload16(Bt + (bn0 + r0) * K + c0, &Bs[0][seg0 << 9]);
  gload16(Bt + (bn0 + r1) * K + c1, &Bs[0][seg1 << 9]);
  gload16(A + (am0 + r0) * K + 32 + c0, &As[1][seg0 << 9]);
  gload16(A + (am0 + r1) * K + 32 + c1, &As[1][seg1 << 9]);
  gload16(Bt + (bn0 + r0) * K + 32 + c0, &Bs[1][seg0 << 9]);
  gload16(Bt + (bn0 + r1) * K + 32 + c1, &Bs[1][seg1 << 9]);

  int cur = 0;
  for (int k0 = 0; k0 < K; k0 += 32) {
    if (k0 + 32 < K)
      asm volatile("s_waitcnt vmcnt(4)" ::: "memory");  // tile k landed; k+1 in flight
    else
      asm volatile("s_waitcnt vmcnt(0)" ::: "memory");  // tail: drain all
    __syncthreads();
    if (k0 + 64 < K) {
      int kn = k0 + 64;
      int nb = cur + 2; if (nb >= 3) nb -= 3;
      gload16(A + (am0 + r0) * K + kn + c0, &As[nb][seg0 << 9]);
      gload16(A + (am0 + r1) * K + kn + c1, &As[nb][seg1 << 9]);
      gload16(Bt + (bn0 + r0) * K + kn + c0, &Bs[nb][seg0 << 9]);
      gload16(Bt + (bn0 + r1) * K + kn + c1, &Bs[nb][seg1 << 9]);
    }
    bf16x8 af[4], bfr[4];
#pragma unroll
    for (int im = 0; im < 4; ++im)
      af[im] = *(const bf16x8*)&As[cur][((wr << 6) + (im << 4) + m16) * 32 + (g << 3)];
#pragma unroll
    for (int in = 0; in < 4; ++in)
      bfr[in] = *(const bf16x8*)&Bs[cur][((wc << 6) + (in << 4) + m16) * 32 + (g << 3)];
    __builtin_amdgcn_s_setprio(1);
#pragma unroll
    for (int im = 0; im < 4; ++im)
#pragma unroll
      for (int in = 0; in < 4; ++in)
        acc[im][in] = MFMA16x16x32(af[im], bfr[in], acc[im][in]);
    __builtin_amdgcn_s_setprio(0);
    cur = cur == 2 ? 0 : cur + 1;
  }

#pragma unroll
  for (int im = 0; im < 4; ++im) {
#pragma unroll
    for (int in = 0; in < 4; ++in) {
      long col = bn0 + (wc << 6) + (in << 4) + m16;
      float bval = bias[col];
#pragma unroll
      for (int r = 0; r < 4; ++r) {
        long row = am0 + (wr << 6) + (im << 4) + (g << 2) + r;
        float v = acc[im][in][r] + bval;
        if (BF16OUT)
          ((unsigned short*)Cv)[row * N + col] = f2bf(v);
        else
          ((float*)Cv)[row * N + col] = v;
      }
    }
  }
}

// ---------------- causal flash attention (KVBLK=64, dbuf, rotated barrier) ----------
// (unchanged from round 13 -- control)
__global__ __launch_bounds__(256, 3) void attn_fwd(const unsigned short* __restrict__ qkv,
                                                   unsigned short* __restrict__ out) {
  const int D3 = 3072;
  const float C1 = 0.18033688f;    // 0.125 * log2(e)
  const float THR = 11.5415603f;   // 8 * log2(e)
  __shared__ __align__(128) unsigned short Ks[2][4096];
  __shared__ __align__(128) unsigned short Vs[2][4096];
  int b = blockIdx.x >> 4, h = blockIdx.x & 15;
  int yy = blockIdx.y;
  int qt = (yy & 1) ? (31 - (yy >> 1)) : (yy >> 1);  // heavy/light interleave
  int t = threadIdx.x;
  int w = t >> 6, l = t & 63;
  int g = l >> 4, m16 = l & 15;
  long base = (long)b * 2048 * D3;
  const unsigned short* kbase = qkv + base + 1024 + h * 64;
  const unsigned short* vbase = qkv + base + 2048 + h * 64;

  int l8 = l >> 3, sc = l & 7;
  int kof = (w * 8 + l8) * D3 + ((sc ^ l8) << 3);
  int s0 = w * 8 + l8;  // V subtile: db = s>>4, kb = s&15; load 1 is +32 elems (db+2)
  int vof = ((s0 & 15) * 4 + (sc >> 1)) * D3 + ((s0 >> 4) << 4) + ((sc & 1) << 3);
  const f32x4 zero4 = (f32x4){0.f, 0.f, 0.f, 0.f};

  int qrow = (qt << 6) + (w << 4) + m16;
  const unsigned short* qp = qkv + base + (long)qrow * D3 + h * 64;
  bf16x8 qf0 = *(const bf16x8*)(qp + g * 8);
  bf16x8 qf1 = *(const bf16x8*)(qp + 32 + g * 8);

  f32x4 O[4];
#pragma unroll
  for (int d = 0; d < 4; ++d) O[d] = zero4;
  f32x4 lsv = zero4;
  float m2 = -1e30f;
  int nt = qt + 1;  // supersteps of 64 keys

  // prologue: stage tile 0 into buf 0
  gload16(kbase + kof, &Ks[0][w << 9]);
  gload16(kbase + 32 * D3 + kof, &Ks[0][2048 + (w << 9)]);
  gload16(vbase + vof, &Vs[0][w << 9]);
  gload16(vbase + vof + 32, &Vs[0][2048 + (w << 9)]);

  int buf = 0;
  for (int ss = 0; ss < nt; ++ss) {
    asm volatile("s_waitcnt vmcnt(0)" ::: "memory");  // own stage for cur tile landed
    __syncthreads();  // all waves' stages visible; all done reading buf^1
    if (ss + 1 < nt) {
      long off = (long)(ss + 1) * 64 * D3;
      gload16(kbase + off + kof, &Ks[buf ^ 1][w << 9]);
      gload16(kbase + off + 32 * D3 + kof, &Ks[buf ^ 1][2048 + (w << 9)]);
      gload16(vbase + off + vof, &Vs[buf ^ 1][w << 9]);
      gload16(vbase + off + vof + 32, &Vs[buf ^ 1][2048 + (w << 9)]);
    }

    // V transpose-reads issued early; latency hides under QK^T + softmax.
    unsigned va = ldsoff(&Vs[buf][0]) + (g << 7) + (m16 << 3);
    bf16x4 t0[4], t1[4], t2[4], t3[4];
#pragma unroll
    for (int d = 0; d < 4; ++d) {
      unsigned a = va + (d << 11);
      TRR(t0[d], a);          // kb = g    -> keys 4g..4g+3
      TRR(t1[d], a + 512);    // kb = g+4  -> keys 16+4g..
      TRR(t2[d], a + 1024);   // kb = 8+g  -> keys 32+4g..
      TRR(t3[d], a + 1536);   // kb = 12+g -> keys 48+4g..
    }
    // K fragments (swizzled) + QK^T
    const char* kbuf = (const char*)&Ks[buf][0];
    int swz = m16 & 7;
    f32x4 st[4];
    __builtin_amdgcn_s_setprio(1);
#pragma unroll
    for (int T = 0; T < 4; ++T) {
      const char* rp = kbuf + (((T << 4) + m16) << 7);
      bf16x8 kf0 = *(const bf16x8*)(rp + ((g ^ swz) << 4));
      bf16x8 kf1 = *(const bf16x8*)(rp + (((4 + g) ^ swz) << 4));
      st[T] = MFMA16x16x32(kf0, qf0, zero4);
      st[T] = MFMA16x16x32(kf1, qf1, st[T]);
    }
    __builtin_amdgcn_s_setprio(0);

    // C layout: col = q = m16, row(T,g,r) -> key = ss*64 + T*16 + g*4 + r
    if (ss == nt - 1) {  // diagonal superstep (wave-uniform branch)
      int rq = qrow - (ss << 6);
#pragma unroll
      for (int T = 0; T < 4; ++T)
#pragma unroll
        for (int r = 0; r < 4; ++r)
          if ((T << 4) + (g << 2) + r > rq) st[T][r] = -3e38f;
    }
    float tm[4];
#pragma unroll
    for (int T = 0; T < 4; ++T)
      tm[T] = max3f(fmaxf(st[T][0], st[T][1]), st[T][2], st[T][3]);
    float tmax = fmaxf(max3f(tm[0], tm[1], tm[2]), tm[3]);
    tmax = fmaxf(tmax, __shfl_xor(tmax, 16));
    tmax = fmaxf(tmax, __shfl_xor(tmax, 32));
    float tsc2 = tmax * C1;
    bool skip = __all(tsc2 <= m2 + THR);  // defer-max (T13)
    float mnew2 = skip ? m2 : fmaxf(m2, tsc2);
    float p[4][4];
    f32x4 ts4 = zero4;
#pragma unroll
    for (int T = 0; T < 4; ++T)
#pragma unroll
      for (int r = 0; r < 4; ++r) {
        float e = __builtin_amdgcn_exp2f(fmaf(st[T][r], C1, -mnew2));
        p[T][r] = e;
        ts4[r] += e;
      }
    if (!skip) {
      float alpha = __builtin_amdgcn_exp2f(m2 - mnew2);
      lsv *= alpha;
#pragma unroll
      for (int d = 0; d < 4; ++d) O[d] *= alpha;
      m2 = mnew2;
    }
    lsv += ts4;

    i32x4 w0, w1;
    w0[0] = cvtpk(p[0][0], p[0][1]); w0[1] = cvtpk(p[0][2], p[0][3]);
    w0[2] = cvtpk(p[1][0], p[1][1]); w0[3] = cvtpk(p[1][2], p[1][3]);
    w1[0] = cvtpk(p[2][0], p[2][1]); w1[1] = cvtpk(p[2][2], p[2][3]);
    w1[2] = cvtpk(p[3][0], p[3][1]); w1[3] = cvtpk(p[3][2], p[3][3]);
    bf16x8 pb0 = __builtin_bit_cast(bf16x8, w0);
    bf16x8 pb1 = __builtin_bit_cast(bf16x8, w1);

    asm volatile("s_waitcnt lgkmcnt(0)" ::: "memory");
    __builtin_amdgcn_sched_barrier(0);

    bf16x8 vfA[4], vfB[4];
#pragma unroll
    for (int d = 0; d < 4; ++d) {
      vfA[d] = __builtin_shufflevector(t0[d], t1[d], 0, 1, 2, 3, 4, 5, 6, 7);
      vfB[d] = __builtin_shufflevector(t2[d], t3[d], 0, 1, 2, 3, 4, 5, 6, 7);
    }
    __builtin_amdgcn_s_setprio(1);
#pragma unroll
    for (int d = 0; d < 4; ++d) {
      O[d] = MFMA16x16x32(vfA[d], pb0, O[d]);
      O[d] = MFMA16x16x32(vfB[d], pb1, O[d]);
    }
    __builtin_amdgcn_s_setprio(0);
    buf ^= 1;  // no trailing barrier: next iteration's vmcnt+barrier covers it
  }

  float s = (lsv[0] + lsv[1]) + (lsv[2] + lsv[3]);
  s += __shfl_xor(s, 16);
  s += __shfl_xor(s, 32);
  float inv = 1.0f / s;
  unsigned short* op = out + (long)(b * 2048 + qrow) * 1024 + h * 64;
#pragma unroll
  for (int d = 0; d < 4; ++d) {
    i32x2 pk;
    pk[0] = (int)cvtpk(O[d][0] * inv, O[d][1] * inv);
    pk[1] = (int)cvtpk(O[d][2] * inv, O[d][3] * inv);
    *reinterpret_cast<i32x2*>(op + (d << 4) + (g << 2)) = pk;
  }
}

extern "C" void kernel_launch(void* const* d_in, const int* in_sizes, int n_in,
                              void* d_out, int out_size, void* d_ws, size_t ws_size,
                              hipStream_t stream) {
  const float* x     = (const float*)d_in[0];
  const float* W_qkv = (const float*)d_in[1];
  const float* b_qkv = (const float*)d_in[2];
  const float* W_out = (const float*)d_in[3];
  const float* b_out = (const float*)d_in[4];

  char* ws = (char*)d_ws;
  unsigned short* xb    = (unsigned short*)ws;                  // 8 MB (x bf16; reused as attn out)
  unsigned short* wqkvT = (unsigned short*)(ws + (8l << 20));   // 6 MB
  unsigned short* woutT = (unsigned short*)(ws + (14l << 20));  // 2 MB
  unsigned short* qkv   = (unsigned short*)(ws + (16l << 20));  // 24 MB

  prep<<<6144, 256, 0, stream>>>(x, xb, W_qkv, wqkvT, W_out, woutT);
  gemm_bt<1><<<dim3(24, 32), 256, 0, stream>>>(xb, wqkvT, b_qkv, (void*)qkv, 4096, 3072, 1024);
  attn_fwd<<<dim3(32, 32), 256, 0, stream>>>(qkv, xb);
  gemm_bt<0><<<dim3(8, 32), 256, 0, stream>>>(xb, woutT, b_out, d_out, 4096, 1024, 1024);
}